// Round 1
// baseline (10.697 us; speedup 1.0000x reference)
//
#include <hip/hip_runtime.h>
#include <hip/hip_bf16.h>

// QNN_10677288698276 — closed-form evaluation.
//
// Heisenberg-picture reduction of the reference circuit (H + RZ(x) encoding,
// 2 layers of per-qubit RY + CNOT chain, measure <Z_0>):
//
//   U† Z0 U = c2*(c10 Z0 - s10 X0) - s2*(c10 X0 + s10 Z0)(c11 X1 + s11 Z1)
//
// with c2=cos(W[o,0,1]), s2=sin(W[o,0,1]), c10=cos(W[o,0,0]),
// s10=sin(W[o,0,0]), c11=cos(W[o,1,0]) (full angles; the chain conjugation
// only spreads X0 -> X0 X1 because C(0,1) is the outermost conjugation).
//
// Encoded product state has <Z_q>=0, <X_q>=cos(x_q), and expectations
// factorize, so:
//
//   out[o,b] = -c2*s10*cos(x[b,0]) - s2*c10*c11*cos(x[b,0])*cos(x[b,1])
//
// Exact in exact arithmetic; fp32 trig error ~1e-7 << 1.98e-2 threshold.

#define OUT_FEATURES 32
#define N_BATCH      128
#define N_QUBITS     12
#define N_LAYERS     2
#define N_OUT        (OUT_FEATURES * N_BATCH)

__global__ void qnn_closed_form(const float* __restrict__ x,
                                const float* __restrict__ w,
                                float* __restrict__ out) {
    int i = blockIdx.x * blockDim.x + threadIdx.x;
    if (i >= N_OUT) return;
    int o = i >> 7;      // / N_BATCH
    int b = i & 127;     // % N_BATCH

    // weight[o, q, l] at w[o*24 + q*2 + l]
    const float w00 = w[o * (N_QUBITS * N_LAYERS) + 0];  // W[o,0,0] (layer 0, qubit 0)
    const float w01 = w[o * (N_QUBITS * N_LAYERS) + 1];  // W[o,0,1] (layer 1, qubit 0)
    const float w10 = w[o * (N_QUBITS * N_LAYERS) + 2];  // W[o,1,0] (layer 0, qubit 1)

    const float x0 = x[b * N_QUBITS + 0];
    const float x1 = x[b * N_QUBITS + 1];

    float s10, c10, s2, c2;
    sincosf(w00, &s10, &c10);
    sincosf(w01, &s2, &c2);
    const float c11 = cosf(w10);
    const float cx0 = cosf(x0);
    const float cx1 = cosf(x1);

    out[i] = -c2 * s10 * cx0 - s2 * c10 * c11 * cx0 * cx1;
}

extern "C" void kernel_launch(void* const* d_in, const int* in_sizes, int n_in,
                              void* d_out, int out_size, void* d_ws, size_t ws_size,
                              hipStream_t stream) {
    const float* x = (const float*)d_in[0];   // [128, 12] f32
    const float* w = (const float*)d_in[1];   // [32, 12, 2] f32
    float* out = (float*)d_out;               // [32, 128] f32

    (void)in_sizes; (void)n_in; (void)out_size; (void)d_ws; (void)ws_size;

    const int block = 256;
    const int grid = (N_OUT + block - 1) / block;  // 16
    qnn_closed_form<<<grid, block, 0, stream>>>(x, w, out);
}